// Round 1
// 385.876 us; speedup vs baseline: 1.0025x; 1.0025x over previous
//
#include <hip/hip_runtime.h>

// ---------------------------------------------------------------------------
// DoshaGAT: 3-layer GAT. R5:
//  - gat_aggregate edge loop scalarized: dst-node state (row/end) and edge
//    sources s[j] forced wave-uniform via readfirstlane -> csr reads become
//    s_load_dwordx8, gathers become saddr-form global_load with 32-bit
//    voffset (s*rowbytes + lane*off fits u32). Cuts ~60 -> ~17 VALU/edge.
//  - l3_agg row bounds scalarized the same way.
// h layout: bf16, head-block-permuted (phys p = c16*CF+cf <-> logical
// L = cf*16+c16 within each head block); consumers re-index by the fixed perm.
// ---------------------------------------------------------------------------

#define WSZ 64

typedef short short8 __attribute__((ext_vector_type(8)));
typedef short short4v __attribute__((ext_vector_type(4)));
typedef float float4v __attribute__((ext_vector_type(4)));

__device__ inline unsigned short f2bf(float f) {  // RNE f32->bf16
  unsigned u = __float_as_uint(f);
  u += 0x7FFFu + ((u >> 16) & 1u);
  return (unsigned short)(u >> 16);
}
__device__ inline float bf2f(unsigned short u) {
  return __uint_as_float(((unsigned)u) << 16);
}

// ---------------- CSR build ----------------

__global__ __launch_bounds__(256) void hist_kernel(const int* __restrict__ dst, int E,
                                                   int* __restrict__ deg) {
  int e = blockIdx.x * 256 + threadIdx.x;
  if (e < E) atomicAdd(&deg[dst[e]], 1);
}

__global__ __launch_bounds__(256) void block_sums_kernel(const int* __restrict__ deg, int n,
                                                         int* __restrict__ bsum) {
  __shared__ int sh[256];
  int t = threadIdx.x;
  int base = blockIdx.x * 1024 + t * 4;
  int v = 0;
#pragma unroll
  for (int j = 0; j < 4; ++j) {
    int idx = base + j;
    if (idx < n) v += deg[idx];
  }
  sh[t] = v;
  __syncthreads();
  for (int off = 128; off >= 1; off >>= 1) {
    if (t < off) sh[t] += sh[t + off];
    __syncthreads();
  }
  if (t == 0) bsum[blockIdx.x] = sh[0];
}

__global__ void tiny_scan_kernel(int* bsum, int nb) {
  if (threadIdx.x == 0 && blockIdx.x == 0) {
    int run = 0;
    for (int i = 0; i < nb; ++i) {
      int v = bsum[i];
      bsum[i] = run;
      run += v;
    }
  }
}

__global__ __launch_bounds__(256) void scan_write_kernel(const int* __restrict__ deg, int n,
                                                         const int* __restrict__ bbase,
                                                         int* __restrict__ row_start,
                                                         int* __restrict__ cursor) {
  __shared__ int sh[256];
  int t = threadIdx.x;
  int base = blockIdx.x * 1024 + t * 4;
  int v[4];
  int s = 0;
#pragma unroll
  for (int j = 0; j < 4; ++j) {
    int idx = base + j;
    v[j] = (idx < n) ? deg[idx] : 0;
    s += v[j];
  }
  sh[t] = s;
  __syncthreads();
  for (int off = 1; off < 256; off <<= 1) {
    int x = (t >= off) ? sh[t - off] : 0;
    __syncthreads();
    sh[t] += x;
    __syncthreads();
  }
  int excl = sh[t] - s + bbase[blockIdx.x];
#pragma unroll
  for (int j = 0; j < 4; ++j) {
    int idx = base + j;
    if (idx < n) {
      row_start[idx] = excl;
      cursor[idx] = excl;
    }
    excl += v[j];
  }
  if (blockIdx.x == gridDim.x - 1 && t == 255) row_start[n] = excl;  // == E
}

__global__ __launch_bounds__(256) void scatter_kernel(const int* __restrict__ src,
                                                      const int* __restrict__ dst, int E,
                                                      int* __restrict__ cursor,
                                                      int* __restrict__ csr_src) {
  int e = blockIdx.x * 256 + threadIdx.x;
  if (e < E) {
    int d = dst[e];
    int p = atomicAdd(&cursor[d], 1);
    csr_src[p] = src[e];
  }
}

// ---------------- weight conversion ----------------

// W1 [128][256] -> W1t [256][128] bf16
__global__ __launch_bounds__(256) void conv_w1t_kernel(const float* __restrict__ W1,
                                                       unsigned short* __restrict__ W1t) {
  int idx = blockIdx.x * 256 + threadIdx.x;  // 32768
  int n = idx >> 7, k = idx & 127;
  W1t[idx] = f2bf(W1[k * 256 + n]);
}

// W2 [256][128] -> W2t [128][256] bf16, K rows permuted to layer-1 phys layout
__global__ __launch_bounds__(256) void conv_w2t_kernel(const float* __restrict__ W2,
                                                       unsigned short* __restrict__ W2t) {
  int idx = blockIdx.x * 256 + threadIdx.x;  // 32768
  int n = idx >> 8, p = idx & 255;
  int kl = (p & ~63) | ((p & 3) << 4) | ((p >> 2) & 15);
  W2t[idx] = f2bf(W2[kl * 128 + n]);
}

// ---------------- bf16 MFMA GEMM + fused attn-coeff epilogue ----------------
// C[M,BN] = A[M,K] @ B[K,BN]. 64-row blocks, 256 threads, 4 waves (wave=head).
// AF32: A is f32, converted to bf16 during LDS staging.

template <int K, int BN, bool AF32>
__global__ __launch_bounds__(256) void gemm_mfma(
    const void* __restrict__ Ap,            // [M][K] bf16 or f32
    const unsigned short* __restrict__ Bt,  // [BN][K] bf16 (pre-transposed)
    const float* __restrict__ a_s, const float* __restrict__ a_d,  // [BN] logical
    unsigned short* __restrict__ hout,      // [M][BN] bf16 physical layout
    float* __restrict__ als, float* __restrict__ ald,  // [M][4]
    int M) {
  constexpr int CF = BN / 64;  // col frags per wave
  constexpr int PAD = 36;
  __shared__ unsigned short As[64][PAD];
  __shared__ unsigned short Bs[BN][PAD];
  const int t = threadIdx.x;
  const int w = t >> 6;
  const int lane = t & 63;
  const int c16 = lane & 15;
  const int q = lane >> 4;
  const int bm = blockIdx.x * 64;
  const int arow = t >> 2;      // 0..63
  const int akc = (t & 3) * 8;  // 0,8,16,24

  float4v acc[4][CF];
#pragma unroll
  for (int rf = 0; rf < 4; ++rf)
#pragma unroll
    for (int cf = 0; cf < CF; ++cf) acc[rf][cf] = float4v{0.f, 0.f, 0.f, 0.f};

  for (int k0 = 0; k0 < K; k0 += 32) {
    {  // stage A tile 64x32 (8 elems/thread)
      int gr = bm + arow;
      if constexpr (AF32) {
        const float* Af = (const float*)Ap + (size_t)gr * K + k0 + akc;
        float4 v0 = make_float4(0.f, 0.f, 0.f, 0.f), v1 = v0;
        if (gr < M) {
          v0 = *(const float4*)Af;
          v1 = *(const float4*)(Af + 4);
        }
        ushort4 u0, u1;
        u0.x = f2bf(v0.x); u0.y = f2bf(v0.y); u0.z = f2bf(v0.z); u0.w = f2bf(v0.w);
        u1.x = f2bf(v1.x); u1.y = f2bf(v1.y); u1.z = f2bf(v1.z); u1.w = f2bf(v1.w);
        *(ushort4*)&As[arow][akc] = u0;
        *(ushort4*)&As[arow][akc + 4] = u1;
      } else {
        uint4 v = make_uint4(0u, 0u, 0u, 0u);
        if (gr < M) v = *(const uint4*)((const unsigned short*)Ap + (size_t)gr * K + k0 + akc);
        *(uint2*)&As[arow][akc] = make_uint2(v.x, v.y);
        *(uint2*)&As[arow][akc + 4] = make_uint2(v.z, v.w);
      }
    }
#pragma unroll
    for (int h = 0; h < BN / 64; ++h) {  // stage B tile BNx32
      int n = (t >> 2) + h * 64;
      uint4 v = *(const uint4*)(Bt + (size_t)n * K + k0 + akc);
      *(uint2*)&Bs[n][akc] = make_uint2(v.x, v.y);
      *(uint2*)&Bs[n][akc + 4] = make_uint2(v.z, v.w);
    }
    __syncthreads();
    short8 af[4], bfr[CF];
#pragma unroll
    for (int rf = 0; rf < 4; ++rf) {
      short4v lo = *(short4v*)&As[rf * 16 + c16][q * 8];
      short4v hi = *(short4v*)&As[rf * 16 + c16][q * 8 + 4];
      af[rf] = __builtin_shufflevector(lo, hi, 0, 1, 2, 3, 4, 5, 6, 7);
    }
#pragma unroll
    for (int cf = 0; cf < CF; ++cf) {
      int n = w * (CF * 16) + cf * 16 + c16;
      short4v lo = *(short4v*)&Bs[n][q * 8];
      short4v hi = *(short4v*)&Bs[n][q * 8 + 4];
      bfr[cf] = __builtin_shufflevector(lo, hi, 0, 1, 2, 3, 4, 5, 6, 7);
    }
#pragma unroll
    for (int rf = 0; rf < 4; ++rf)
#pragma unroll
      for (int cf = 0; cf < CF; ++cf)
        acc[rf][cf] =
            __builtin_amdgcn_mfma_f32_16x16x32_bf16(af[rf], bfr[cf], acc[rf][cf], 0, 0, 0);
    __syncthreads();
  }

  float sasv[CF], sadv[CF];
#pragma unroll
  for (int cf = 0; cf < CF; ++cf) {
    int L = w * (CF * 16) + cf * 16 + c16;
    sasv[cf] = a_s[L];
    sadv[cf] = a_d[L];
  }
#pragma unroll
  for (int rf = 0; rf < 4; ++rf) {
#pragma unroll
    for (int r = 0; r < 4; ++r) {
      int n = bm + rf * 16 + q * 4 + r;
      float ps = 0.f, pd = 0.f;
      unsigned short us[CF];
#pragma unroll
      for (int cf = 0; cf < CF; ++cf) {
        float v = acc[rf][cf][r];
        us[cf] = f2bf(v);
        ps += v * sasv[cf];
        pd += v * sadv[cf];
      }
#pragma unroll
      for (int off = 1; off <= 8; off <<= 1) {
        ps += __shfl_xor(ps, off, 16);
        pd += __shfl_xor(pd, off, 16);
      }
      if (n < M) {
        if constexpr (CF == 4) {
          ushort4 u;
          u.x = us[0]; u.y = us[1]; u.z = us[2]; u.w = us[3];
          *(ushort4*)(hout + (size_t)n * BN + w * 64 + c16 * 4) = u;
        } else {
          ushort2 u;
          u.x = us[0]; u.y = us[1];
          *(ushort2*)(hout + (size_t)n * BN + w * 32 + c16 * 2) = u;
        }
        if (c16 == 0) {
          als[(size_t)n * 4 + w] = ps;
          ald[(size_t)n * 4 + w] = pd;
        }
      }
    }
  }
}

// ---------------- GAT aggregation + bias + BN + ELU (+ fused layer-3 prep) --
// One wave per dst node; lane feature-parallel (phys cols); bf16 gather;
// 8-edge software pipeline; f32 accumulation.
// R5: dst-node row bounds and per-edge src indices are wave-uniform -> forced
// into SGPRs via readfirstlane. csr reads compile to s_load_dwordx8; gathers
// use saddr-form global_load with a 32-bit voffset (N*rowbytes < 4 GB), so
// per-edge addressing is 1 v_lshl_add_u32 per load instead of 64-bit chains.

template <int D, bool FUSEL3>
__global__ __launch_bounds__(256) void gat_aggregate(
    const unsigned short* __restrict__ h_bf, const float* __restrict__ als,
    const float* __restrict__ ald, const int* __restrict__ row_start,
    const int* __restrict__ csr_src, const float* __restrict__ bias,
    const float* __restrict__ gamma, const float* __restrict__ beta,
    const float* __restrict__ bmean, const float* __restrict__ bvar,
    unsigned short* __restrict__ obf,  // D==256 output
    const float* __restrict__ W3, const float* __restrict__ a3s,
    const float* __restrict__ a3d, float4* __restrict__ h3p,
    float* __restrict__ ald3,  // FUSEL3 outputs
    int n_nodes) {
  constexpr int VPT = D / WSZ;
  constexpr int H = 4;
  __shared__ float w3s[384];
  __shared__ float sa3[6];
  if constexpr (FUSEL3) {
    for (int i = threadIdx.x; i < 384; i += 256) w3s[i] = W3[i];
    if (threadIdx.x < 3) {
      sa3[threadIdx.x] = a3s[threadIdx.x];
      sa3[3 + threadIdx.x] = a3d[threadIdx.x];
    }
    __syncthreads();
  }
  int wid = threadIdx.x >> 6, lane = threadIdx.x & 63;
  int n = __builtin_amdgcn_readfirstlane(blockIdx.x * 4 + wid);  // wave-uniform
  if (n >= n_nodes) return;  // N%4==0: never taken, kept for safety
  int hd = lane >> 4;                                 // head
  const unsigned coff = (unsigned)(lane * VPT * 2);   // byte off in h row
  const unsigned aoff = (unsigned)(hd * 4);           // byte off in als row
  const char* hb = (const char*)h_bf;
  const char* ab = (const char*)als;
  float aldv = ald[(size_t)n * H + hd];
  int row = __builtin_amdgcn_readfirstlane(row_start[n]);
  int end = __builtin_amdgcn_readfirstlane(row_start[n + 1]);
  float acc[VPT] = {};
  float ssum = 0.f;
  int i = row;

#define EDGE_BLOCK(B)                                                          \
  for (; i + (B) <= end; i += (B)) {                                           \
    int s[B];                                                                  \
    _Pragma("unroll") for (int j = 0; j < (B); ++j) s[j] =                     \
        __builtin_amdgcn_readfirstlane(csr_src[i + j]);                        \
    float e[B];                                                                \
    _Pragma("unroll") for (int j = 0; j < (B); ++j) e[j] =                     \
        *(const float*)(ab + ((unsigned)s[j] * 16u + aoff)) + aldv;            \
    if constexpr (VPT == 4) {                                                  \
      ushort4 u[B];                                                            \
      _Pragma("unroll") for (int j = 0; j < (B); ++j) u[j] =                   \
          *(const ushort4*)(hb + ((unsigned)s[j] * (unsigned)(D * 2) + coff)); \
      _Pragma("unroll") for (int j = 0; j < (B); ++j) {                        \
        float ee = fmaxf(e[j], 0.2f * e[j]);                                   \
        float ex = __expf(ee);                                                 \
        ssum += ex;                                                            \
        acc[0] += ex * bf2f(u[j].x);                                           \
        acc[1] += ex * bf2f(u[j].y);                                           \
        acc[2] += ex * bf2f(u[j].z);                                           \
        acc[3] += ex * bf2f(u[j].w);                                           \
      }                                                                        \
    } else {                                                                   \
      ushort2 u[B];                                                            \
      _Pragma("unroll") for (int j = 0; j < (B); ++j) u[j] =                   \
          *(const ushort2*)(hb + ((unsigned)s[j] * (unsigned)(D * 2) + coff)); \
      _Pragma("unroll") for (int j = 0; j < (B); ++j) {                        \
        float ee = fmaxf(e[j], 0.2f * e[j]);                                   \
        float ex = __expf(ee);                                                 \
        ssum += ex;                                                            \
        acc[0] += ex * bf2f(u[j].x);                                           \
        acc[1] += ex * bf2f(u[j].y);                                           \
      }                                                                        \
    }                                                                          \
  }

  EDGE_BLOCK(8)
  EDGE_BLOCK(4)
  EDGE_BLOCK(1)
#undef EDGE_BLOCK

  float inv = 1.f / (ssum + 1e-16f);
#pragma unroll
  for (int j = 0; j < VPT; ++j) {
    int cl = hd * (VPT * 16) + j * 16 + (lane & 15);  // logical col
    float o = acc[j] * inv + bias[cl];
    o = (o - bmean[cl]) * rsqrtf(bvar[cl] + 1e-5f) * gamma[cl] + beta[cl];
    o = (o > 0.f) ? o : (__expf(o) - 1.f);  // ELU
    acc[j] = o;
  }
  if constexpr (!FUSEL3) {
    ushort4 u;
    u.x = f2bf(acc[0]); u.y = f2bf(acc[1]); u.z = f2bf(acc[2]); u.w = f2bf(acc[3]);
    *(ushort4*)(obf + (size_t)n * D + (lane * VPT)) = u;
  } else {
    // fused l3_prep: o2 row lives in acc[0..1] (phys cols lane*2, lane*2+1).
    int k0l = hd * 32 + (lane & 15);  // logical k of acc[0]
    int k1l = k0l + 16;               // logical k of acc[1]
    float p0 = acc[0] * w3s[k0l * 3 + 0] + acc[1] * w3s[k1l * 3 + 0];
    float p1 = acc[0] * w3s[k0l * 3 + 1] + acc[1] * w3s[k1l * 3 + 1];
    float p2 = acc[0] * w3s[k0l * 3 + 2] + acc[1] * w3s[k1l * 3 + 2];
#pragma unroll
    for (int off = 32; off >= 1; off >>= 1) {
      p0 += __shfl_xor(p0, off, 64);
      p1 += __shfl_xor(p1, off, 64);
      p2 += __shfl_xor(p2, off, 64);
    }
    if (lane == 0) {
      float als3 = p0 * sa3[0] + p1 * sa3[1] + p2 * sa3[2];
      float ad3 = p0 * sa3[3] + p1 * sa3[4] + p2 * sa3[5];
      h3p[n] = make_float4(p0, p1, p2, als3);
      ald3[n] = ad3;
    }
  }
}

// ---------------- layer 3 aggregation + log_softmax -------------------------

__global__ __launch_bounds__(256) void l3_agg_kernel(const float4* __restrict__ h3p,
                                                     const float* __restrict__ ald3,
                                                     const int* __restrict__ row_start,
                                                     const int* __restrict__ csr_src,
                                                     const float* __restrict__ b3,
                                                     float* __restrict__ out, int n_nodes) {
  int wid = threadIdx.x >> 6, lane = threadIdx.x & 63;
  int n = __builtin_amdgcn_readfirstlane(blockIdx.x * 4 + wid);
  if (n >= n_nodes) return;
  float aldv = ald3[n];
  int row = __builtin_amdgcn_readfirstlane(row_start[n]);
  int end = __builtin_amdgcn_readfirstlane(row_start[n + 1]);
  const char* hp = (const char*)h3p;
  float a0 = 0.f, a1 = 0.f, a2 = 0.f, ss = 0.f;
  for (int i = row + lane; i < end; i += 64) {
    int s = csr_src[i];
    float4 hv = *(const float4*)(hp + ((unsigned)s * 16u));
    float e = hv.w + aldv;
    e = fmaxf(e, 0.2f * e);
    float ex = __expf(e);
    ss += ex;
    a0 += ex * hv.x;
    a1 += ex * hv.y;
    a2 += ex * hv.z;
  }
#pragma unroll
  for (int off = 32; off >= 1; off >>= 1) {
    a0 += __shfl_xor(a0, off, 64);
    a1 += __shfl_xor(a1, off, 64);
    a2 += __shfl_xor(a2, off, 64);
    ss += __shfl_xor(ss, off, 64);
  }
  if (lane == 0) {
    float inv = 1.f / (ss + 1e-16f);
    float o0 = a0 * inv + b3[0];
    float o1 = a1 * inv + b3[1];
    float o2 = a2 * inv + b3[2];
    float m = fmaxf(o0, fmaxf(o1, o2));
    float lse = m + logf(expf(o0 - m) + expf(o1 - m) + expf(o2 - m));
    out[n * 3 + 0] = o0 - lse;
    out[n * 3 + 1] = o1 - lse;
    out[n * 3 + 2] = o2 - lse;
  }
}

// ---------------------------------------------------------------------------

extern "C" void kernel_launch(void* const* d_in, const int* in_sizes, int n_in,
                              void* d_out, int out_size, void* d_ws, size_t ws_size,
                              hipStream_t stream) {
  const float* x   = (const float*)d_in[0];
  const int*   ei  = (const int*)d_in[1];
  const float* W1  = (const float*)d_in[2];
  const float* a1s = (const float*)d_in[3];
  const float* a1d = (const float*)d_in[4];
  const float* b1  = (const float*)d_in[5];
  const float* g1v = (const float*)d_in[6];
  const float* be1 = (const float*)d_in[7];
  const float* m1  = (const float*)d_in[8];
  const float* v1  = (const float*)d_in[9];
  const float* W2  = (const float*)d_in[10];
  const float* a2s = (const float*)d_in[11];
  const float* a2d = (const float*)d_in[12];
  const float* b2  = (const float*)d_in[13];
  const float* g2v = (const float*)d_in[14];
  const float* be2 = (const float*)d_in[15];
  const float* m2  = (const float*)d_in[16];
  const float* v2  = (const float*)d_in[17];
  const float* W3  = (const float*)d_in[18];
  const float* a3s = (const float*)d_in[19];
  const float* a3d = (const float*)d_in[20];
  const float* b3  = (const float*)d_in[21];
  float* out = (float*)d_out;

  const int N = in_sizes[0] / 128;  // 50000
  const int E = in_sizes[1] / 2;    // 850000
  const int* srcv = ei;
  const int* dstv = ei + E;

  // workspace carve-up (~75 MB)
  float* wsf  = (float*)d_ws;
  float* als1 = wsf;                  // N*4
  float* ald1 = als1 + (size_t)N * 4;
  float* als2 = ald1 + (size_t)N * 4;
  float* ald2 = als2 + (size_t)N * 4;
  float* h3p  = ald2 + (size_t)N * 4;  // N*4 (float4 rows)
  float* ald3 = h3p + (size_t)N * 4;   // N
  unsigned short* h_bf1 = (unsigned short*)(ald3 + N);  // N*256
  unsigned short* o1_bf = h_bf1 + (size_t)N * 256;      // N*256
  unsigned short* h_bf2 = o1_bf + (size_t)N * 256;      // N*128
  unsigned short* W1t   = h_bf2 + (size_t)N * 128;      // 256*128
  unsigned short* W2t   = W1t + 256 * 128;              // 128*256
  int* deg       = (int*)(W2t + 128 * 256);  // N
  int* row_start = deg + N;                  // N+1
  int* cursor    = row_start + (N + 1);      // N+1
  int* csr_src   = cursor + (N + 1);         // E
  int* bsum      = csr_src + E;              // 1024

  const int eb = (E + 255) / 256;
  const int nb = (N + 1023) / 1024;
  const int nodes4 = (N + 3) / 4;
  const int mblocks = (N + 63) / 64;

  // weight conversions
  conv_w1t_kernel<<<128, 256, 0, stream>>>(W1, W1t);
  conv_w2t_kernel<<<128, 256, 0, stream>>>(W2, W2t);

  // CSR build (shared by all 3 layers)
  hipMemsetAsync(deg, 0, (size_t)N * sizeof(int), stream);
  hist_kernel<<<eb, 256, 0, stream>>>(dstv, E, deg);
  block_sums_kernel<<<nb, 256, 0, stream>>>(deg, N, bsum);
  tiny_scan_kernel<<<1, 64, 0, stream>>>(bsum, nb);
  scan_write_kernel<<<nb, 256, 0, stream>>>(deg, N, bsum, row_start, cursor);
  scatter_kernel<<<eb, 256, 0, stream>>>(srcv, dstv, E, cursor, csr_src);

  // layer 1: h1 = x @ W1 (f32 A converted in staging), fused als1/ald1
  gemm_mfma<128, 256, true><<<mblocks, 256, 0, stream>>>(x, W1t, a1s, a1d, h_bf1, als1,
                                                         ald1, N);
  gat_aggregate<256, false><<<nodes4, 256, 0, stream>>>(
      h_bf1, als1, ald1, row_start, csr_src, b1, g1v, be1, m1, v1, o1_bf, nullptr, nullptr,
      nullptr, nullptr, nullptr, N);
  // layer 2
  gemm_mfma<256, 128, false><<<mblocks, 256, 0, stream>>>(o1_bf, W2t, a2s, a2d, h_bf2, als2,
                                                          ald2, N);
  gat_aggregate<128, true><<<nodes4, 256, 0, stream>>>(
      h_bf2, als2, ald2, row_start, csr_src, b2, g2v, be2, m2, v2, nullptr, W3, a3s, a3d,
      (float4*)h3p, ald3, N);
  // layer 3 + log_softmax
  l3_agg_kernel<<<nodes4, 256, 0, stream>>>((const float4*)h3p, ald3, row_start, csr_src,
                                            b3, out, N);
}

// Round 2
// 376.542 us; speedup vs baseline: 1.0274x; 1.0248x over previous
//
#include <hip/hip_runtime.h>

// ---------------------------------------------------------------------------
// DoshaGAT: 3-layer GAT. R6:
//  - gat_aggregate: 2-deep ping-pong software pipeline over 8-edge blocks
//    (ISSUE(k+1) overlaps COMPUTE(k); counted vmcnt keeps next block's 16
//    gathers in flight). Tail removed: last block is a full 8-edge block with
//    csr index clamped to end-1 (dup rows L1-hit) and ex masked to 0.
//  - R5 scalarization retained: row/end/s[j] wave-uniform via readfirstlane,
//    gathers are saddr+u32-voffset form.
// h layout: bf16, head-block-permuted (phys p = c16*CF+cf <-> logical
// L = cf*16+c16 within each head block); consumers re-index by the fixed perm.
// ---------------------------------------------------------------------------

#define WSZ 64

typedef short short8 __attribute__((ext_vector_type(8)));
typedef short short4v __attribute__((ext_vector_type(4)));
typedef float float4v __attribute__((ext_vector_type(4)));

__device__ inline unsigned short f2bf(float f) {  // RNE f32->bf16
  unsigned u = __float_as_uint(f);
  u += 0x7FFFu + ((u >> 16) & 1u);
  return (unsigned short)(u >> 16);
}
__device__ inline float bf2f(unsigned short u) {
  return __uint_as_float(((unsigned)u) << 16);
}

// ---------------- CSR build ----------------

__global__ __launch_bounds__(256) void hist_kernel(const int* __restrict__ dst, int E,
                                                   int* __restrict__ deg) {
  int e = blockIdx.x * 256 + threadIdx.x;
  if (e < E) atomicAdd(&deg[dst[e]], 1);
}

__global__ __launch_bounds__(256) void block_sums_kernel(const int* __restrict__ deg, int n,
                                                         int* __restrict__ bsum) {
  __shared__ int sh[256];
  int t = threadIdx.x;
  int base = blockIdx.x * 1024 + t * 4;
  int v = 0;
#pragma unroll
  for (int j = 0; j < 4; ++j) {
    int idx = base + j;
    if (idx < n) v += deg[idx];
  }
  sh[t] = v;
  __syncthreads();
  for (int off = 128; off >= 1; off >>= 1) {
    if (t < off) sh[t] += sh[t + off];
    __syncthreads();
  }
  if (t == 0) bsum[blockIdx.x] = sh[0];
}

__global__ void tiny_scan_kernel(int* bsum, int nb) {
  if (threadIdx.x == 0 && blockIdx.x == 0) {
    int run = 0;
    for (int i = 0; i < nb; ++i) {
      int v = bsum[i];
      bsum[i] = run;
      run += v;
    }
  }
}

__global__ __launch_bounds__(256) void scan_write_kernel(const int* __restrict__ deg, int n,
                                                         const int* __restrict__ bbase,
                                                         int* __restrict__ row_start,
                                                         int* __restrict__ cursor) {
  __shared__ int sh[256];
  int t = threadIdx.x;
  int base = blockIdx.x * 1024 + t * 4;
  int v[4];
  int s = 0;
#pragma unroll
  for (int j = 0; j < 4; ++j) {
    int idx = base + j;
    v[j] = (idx < n) ? deg[idx] : 0;
    s += v[j];
  }
  sh[t] = s;
  __syncthreads();
  for (int off = 1; off < 256; off <<= 1) {
    int x = (t >= off) ? sh[t - off] : 0;
    __syncthreads();
    sh[t] += x;
    __syncthreads();
  }
  int excl = sh[t] - s + bbase[blockIdx.x];
#pragma unroll
  for (int j = 0; j < 4; ++j) {
    int idx = base + j;
    if (idx < n) {
      row_start[idx] = excl;
      cursor[idx] = excl;
    }
    excl += v[j];
  }
  if (blockIdx.x == gridDim.x - 1 && t == 255) row_start[n] = excl;  // == E
}

__global__ __launch_bounds__(256) void scatter_kernel(const int* __restrict__ src,
                                                      const int* __restrict__ dst, int E,
                                                      int* __restrict__ cursor,
                                                      int* __restrict__ csr_src) {
  int e = blockIdx.x * 256 + threadIdx.x;
  if (e < E) {
    int d = dst[e];
    int p = atomicAdd(&cursor[d], 1);
    csr_src[p] = src[e];
  }
}

// ---------------- weight conversion ----------------

// W1 [128][256] -> W1t [256][128] bf16
__global__ __launch_bounds__(256) void conv_w1t_kernel(const float* __restrict__ W1,
                                                       unsigned short* __restrict__ W1t) {
  int idx = blockIdx.x * 256 + threadIdx.x;  // 32768
  int n = idx >> 7, k = idx & 127;
  W1t[idx] = f2bf(W1[k * 256 + n]);
}

// W2 [256][128] -> W2t [128][256] bf16, K rows permuted to layer-1 phys layout
__global__ __launch_bounds__(256) void conv_w2t_kernel(const float* __restrict__ W2,
                                                       unsigned short* __restrict__ W2t) {
  int idx = blockIdx.x * 256 + threadIdx.x;  // 32768
  int n = idx >> 8, p = idx & 255;
  int kl = (p & ~63) | ((p & 3) << 4) | ((p >> 2) & 15);
  W2t[idx] = f2bf(W2[kl * 128 + n]);
}

// ---------------- bf16 MFMA GEMM + fused attn-coeff epilogue ----------------
// C[M,BN] = A[M,K] @ B[K,BN]. 64-row blocks, 256 threads, 4 waves (wave=head).
// AF32: A is f32, converted to bf16 during LDS staging.

template <int K, int BN, bool AF32>
__global__ __launch_bounds__(256) void gemm_mfma(
    const void* __restrict__ Ap,            // [M][K] bf16 or f32
    const unsigned short* __restrict__ Bt,  // [BN][K] bf16 (pre-transposed)
    const float* __restrict__ a_s, const float* __restrict__ a_d,  // [BN] logical
    unsigned short* __restrict__ hout,      // [M][BN] bf16 physical layout
    float* __restrict__ als, float* __restrict__ ald,  // [M][4]
    int M) {
  constexpr int CF = BN / 64;  // col frags per wave
  constexpr int PAD = 36;
  __shared__ unsigned short As[64][PAD];
  __shared__ unsigned short Bs[BN][PAD];
  const int t = threadIdx.x;
  const int w = t >> 6;
  const int lane = t & 63;
  const int c16 = lane & 15;
  const int q = lane >> 4;
  const int bm = blockIdx.x * 64;
  const int arow = t >> 2;      // 0..63
  const int akc = (t & 3) * 8;  // 0,8,16,24

  float4v acc[4][CF];
#pragma unroll
  for (int rf = 0; rf < 4; ++rf)
#pragma unroll
    for (int cf = 0; cf < CF; ++cf) acc[rf][cf] = float4v{0.f, 0.f, 0.f, 0.f};

  for (int k0 = 0; k0 < K; k0 += 32) {
    {  // stage A tile 64x32 (8 elems/thread)
      int gr = bm + arow;
      if constexpr (AF32) {
        const float* Af = (const float*)Ap + (size_t)gr * K + k0 + akc;
        float4 v0 = make_float4(0.f, 0.f, 0.f, 0.f), v1 = v0;
        if (gr < M) {
          v0 = *(const float4*)Af;
          v1 = *(const float4*)(Af + 4);
        }
        ushort4 u0, u1;
        u0.x = f2bf(v0.x); u0.y = f2bf(v0.y); u0.z = f2bf(v0.z); u0.w = f2bf(v0.w);
        u1.x = f2bf(v1.x); u1.y = f2bf(v1.y); u1.z = f2bf(v1.z); u1.w = f2bf(v1.w);
        *(ushort4*)&As[arow][akc] = u0;
        *(ushort4*)&As[arow][akc + 4] = u1;
      } else {
        uint4 v = make_uint4(0u, 0u, 0u, 0u);
        if (gr < M) v = *(const uint4*)((const unsigned short*)Ap + (size_t)gr * K + k0 + akc);
        *(uint2*)&As[arow][akc] = make_uint2(v.x, v.y);
        *(uint2*)&As[arow][akc + 4] = make_uint2(v.z, v.w);
      }
    }
#pragma unroll
    for (int h = 0; h < BN / 64; ++h) {  // stage B tile BNx32
      int n = (t >> 2) + h * 64;
      uint4 v = *(const uint4*)(Bt + (size_t)n * K + k0 + akc);
      *(uint2*)&Bs[n][akc] = make_uint2(v.x, v.y);
      *(uint2*)&Bs[n][akc + 4] = make_uint2(v.z, v.w);
    }
    __syncthreads();
    short8 af[4], bfr[CF];
#pragma unroll
    for (int rf = 0; rf < 4; ++rf) {
      short4v lo = *(short4v*)&As[rf * 16 + c16][q * 8];
      short4v hi = *(short4v*)&As[rf * 16 + c16][q * 8 + 4];
      af[rf] = __builtin_shufflevector(lo, hi, 0, 1, 2, 3, 4, 5, 6, 7);
    }
#pragma unroll
    for (int cf = 0; cf < CF; ++cf) {
      int n = w * (CF * 16) + cf * 16 + c16;
      short4v lo = *(short4v*)&Bs[n][q * 8];
      short4v hi = *(short4v*)&Bs[n][q * 8 + 4];
      bfr[cf] = __builtin_shufflevector(lo, hi, 0, 1, 2, 3, 4, 5, 6, 7);
    }
#pragma unroll
    for (int rf = 0; rf < 4; ++rf)
#pragma unroll
      for (int cf = 0; cf < CF; ++cf)
        acc[rf][cf] =
            __builtin_amdgcn_mfma_f32_16x16x32_bf16(af[rf], bfr[cf], acc[rf][cf], 0, 0, 0);
    __syncthreads();
  }

  float sasv[CF], sadv[CF];
#pragma unroll
  for (int cf = 0; cf < CF; ++cf) {
    int L = w * (CF * 16) + cf * 16 + c16;
    sasv[cf] = a_s[L];
    sadv[cf] = a_d[L];
  }
#pragma unroll
  for (int rf = 0; rf < 4; ++rf) {
#pragma unroll
    for (int r = 0; r < 4; ++r) {
      int n = bm + rf * 16 + q * 4 + r;
      float ps = 0.f, pd = 0.f;
      unsigned short us[CF];
#pragma unroll
      for (int cf = 0; cf < CF; ++cf) {
        float v = acc[rf][cf][r];
        us[cf] = f2bf(v);
        ps += v * sasv[cf];
        pd += v * sadv[cf];
      }
#pragma unroll
      for (int off = 1; off <= 8; off <<= 1) {
        ps += __shfl_xor(ps, off, 16);
        pd += __shfl_xor(pd, off, 16);
      }
      if (n < M) {
        if constexpr (CF == 4) {
          ushort4 u;
          u.x = us[0]; u.y = us[1]; u.z = us[2]; u.w = us[3];
          *(ushort4*)(hout + (size_t)n * BN + w * 64 + c16 * 4) = u;
        } else {
          ushort2 u;
          u.x = us[0]; u.y = us[1];
          *(ushort2*)(hout + (size_t)n * BN + w * 32 + c16 * 2) = u;
        }
        if (c16 == 0) {
          als[(size_t)n * 4 + w] = ps;
          ald[(size_t)n * 4 + w] = pd;
        }
      }
    }
  }
}

// ---------------- GAT aggregation + bias + BN + ELU (+ fused layer-3 prep) --
// One wave per dst node; lane feature-parallel (phys cols); bf16 gather;
// f32 accumulation.
// R6 pipeline: blocks of 8 edges, 2-deep ping-pong (ISSUE(k+1) before
// COMPUTE(k)); last block clamps csr idx to end-1 (dup row -> L1 hit) and
// masks ex to 0 for out-of-range edges. One exposed gather-wait per node.

template <int D, bool FUSEL3>
__global__ __launch_bounds__(256) void gat_aggregate(
    const unsigned short* __restrict__ h_bf, const float* __restrict__ als,
    const float* __restrict__ ald, const int* __restrict__ row_start,
    const int* __restrict__ csr_src, const float* __restrict__ bias,
    const float* __restrict__ gamma, const float* __restrict__ beta,
    const float* __restrict__ bmean, const float* __restrict__ bvar,
    unsigned short* __restrict__ obf,  // D==256 output
    const float* __restrict__ W3, const float* __restrict__ a3s,
    const float* __restrict__ a3d, float4* __restrict__ h3p,
    float* __restrict__ ald3,  // FUSEL3 outputs
    int n_nodes) {
  constexpr int VPT = D / WSZ;
  constexpr int H = 4;
  __shared__ float w3s[384];
  __shared__ float sa3[6];
  if constexpr (FUSEL3) {
    for (int i = threadIdx.x; i < 384; i += 256) w3s[i] = W3[i];
    if (threadIdx.x < 3) {
      sa3[threadIdx.x] = a3s[threadIdx.x];
      sa3[3 + threadIdx.x] = a3d[threadIdx.x];
    }
    __syncthreads();
  }
  int wid = threadIdx.x >> 6, lane = threadIdx.x & 63;
  int n = __builtin_amdgcn_readfirstlane(blockIdx.x * 4 + wid);  // wave-uniform
  if (n >= n_nodes) return;  // N%4==0: never taken, kept for safety
  int hd = lane >> 4;                                 // head
  const unsigned coff = (unsigned)(lane * VPT * 2);   // byte off in h row
  const unsigned aoff = (unsigned)(hd * 4);           // byte off in als row
  const char* hb = (const char*)h_bf;
  const char* ab = (const char*)als;
  float aldv = ald[(size_t)n * H + hd];
  int row = __builtin_amdgcn_readfirstlane(row_start[n]);
  int end = __builtin_amdgcn_readfirstlane(row_start[n + 1]);
  float acc[VPT] = {};
  float ssum = 0.f;

  // ping-pong banks (static indexing only: rule-#20)
  int sA[8], sB[8];
  float aA[8], aB[8];
  uint2 uA[8], uB[8];  // VPT==2 uses .x only (compiler DCEs .y)

#define ISSUE(sX, aX, uX, iX)                                                    \
  {                                                                              \
    _Pragma("unroll") for (int j = 0; j < 8; ++j) {                              \
      int idx = iX + j;                                                          \
      idx = (idx < end) ? idx : (end - 1);                                       \
      sX[j] = __builtin_amdgcn_readfirstlane(csr_src[idx]);                      \
    }                                                                            \
    _Pragma("unroll") for (int j = 0; j < 8; ++j)                                \
      aX[j] = *(const float*)(ab + ((unsigned)sX[j] * 16u + aoff));              \
    _Pragma("unroll") for (int j = 0; j < 8; ++j) {                              \
      if constexpr (VPT == 4)                                                    \
        uX[j] = *(const uint2*)(hb + ((unsigned)sX[j] * (unsigned)(D * 2) + coff)); \
      else                                                                       \
        uX[j].x = *(const unsigned*)(hb + ((unsigned)sX[j] * (unsigned)(D * 2) + coff)); \
    }                                                                            \
  }

#define COMPUTE(aX, uX, iX)                                                      \
  {                                                                              \
    _Pragma("unroll") for (int j = 0; j < 8; ++j) {                              \
      float e = aX[j] + aldv;                                                    \
      e = fmaxf(e, 0.2f * e);                                                    \
      float ex = __expf(e);                                                      \
      ex = (iX + j < end) ? ex : 0.f;                                            \
      ssum += ex;                                                                \
      if constexpr (VPT == 4) {                                                  \
        acc[0] += ex * __uint_as_float(uX[j].x << 16);                           \
        acc[1] += ex * __uint_as_float(uX[j].x & 0xffff0000u);                   \
        acc[2] += ex * __uint_as_float(uX[j].y << 16);                           \
        acc[3] += ex * __uint_as_float(uX[j].y & 0xffff0000u);                   \
      } else {                                                                   \
        acc[0] += ex * __uint_as_float(uX[j].x << 16);                           \
        acc[1] += ex * __uint_as_float(uX[j].x & 0xffff0000u);                   \
      }                                                                          \
    }                                                                            \
  }

  int deg = end - row;
  if (deg > 0) {
    int F = (deg + 7) >> 3;  // number of 8-edge blocks (last one masked)
    int iA = row, iB = row;
    ISSUE(sA, aA, uA, iA);
    int k = 0;
    for (; k + 2 <= F - 1; k += 2) {
      iB = row + (k + 1) * 8;
      ISSUE(sB, aB, uB, iB);
      COMPUTE(aA, uA, iA);
      iA = row + (k + 2) * 8;
      ISSUE(sA, aA, uA, iA);
      COMPUTE(aB, uB, iB);
    }
    if (k + 1 < F) {
      iB = row + (k + 1) * 8;
      ISSUE(sB, aB, uB, iB);
      COMPUTE(aA, uA, iA);
      COMPUTE(aB, uB, iB);
    } else {
      COMPUTE(aA, uA, iA);
    }
  }
#undef ISSUE
#undef COMPUTE

  float inv = 1.f / (ssum + 1e-16f);
#pragma unroll
  for (int j = 0; j < VPT; ++j) {
    int cl = hd * (VPT * 16) + j * 16 + (lane & 15);  // logical col
    float o = acc[j] * inv + bias[cl];
    o = (o - bmean[cl]) * rsqrtf(bvar[cl] + 1e-5f) * gamma[cl] + beta[cl];
    o = (o > 0.f) ? o : (__expf(o) - 1.f);  // ELU
    acc[j] = o;
  }
  if constexpr (!FUSEL3) {
    ushort4 u;
    u.x = f2bf(acc[0]); u.y = f2bf(acc[1]); u.z = f2bf(acc[2]); u.w = f2bf(acc[3]);
    *(ushort4*)(obf + (size_t)n * D + (lane * VPT)) = u;
  } else {
    // fused l3_prep: o2 row lives in acc[0..1] (phys cols lane*2, lane*2+1).
    int k0l = hd * 32 + (lane & 15);  // logical k of acc[0]
    int k1l = k0l + 16;               // logical k of acc[1]
    float p0 = acc[0] * w3s[k0l * 3 + 0] + acc[1] * w3s[k1l * 3 + 0];
    float p1 = acc[0] * w3s[k0l * 3 + 1] + acc[1] * w3s[k1l * 3 + 1];
    float p2 = acc[0] * w3s[k0l * 3 + 2] + acc[1] * w3s[k1l * 3 + 2];
#pragma unroll
    for (int off = 32; off >= 1; off >>= 1) {
      p0 += __shfl_xor(p0, off, 64);
      p1 += __shfl_xor(p1, off, 64);
      p2 += __shfl_xor(p2, off, 64);
    }
    if (lane == 0) {
      float als3 = p0 * sa3[0] + p1 * sa3[1] + p2 * sa3[2];
      float ad3 = p0 * sa3[3] + p1 * sa3[4] + p2 * sa3[5];
      h3p[n] = make_float4(p0, p1, p2, als3);
      ald3[n] = ad3;
    }
  }
}

// ---------------- layer 3 aggregation + log_softmax -------------------------

__global__ __launch_bounds__(256) void l3_agg_kernel(const float4* __restrict__ h3p,
                                                     const float* __restrict__ ald3,
                                                     const int* __restrict__ row_start,
                                                     const int* __restrict__ csr_src,
                                                     const float* __restrict__ b3,
                                                     float* __restrict__ out, int n_nodes) {
  int wid = threadIdx.x >> 6, lane = threadIdx.x & 63;
  int n = __builtin_amdgcn_readfirstlane(blockIdx.x * 4 + wid);
  if (n >= n_nodes) return;
  float aldv = ald3[n];
  int row = __builtin_amdgcn_readfirstlane(row_start[n]);
  int end = __builtin_amdgcn_readfirstlane(row_start[n + 1]);
  const char* hp = (const char*)h3p;
  float a0 = 0.f, a1 = 0.f, a2 = 0.f, ss = 0.f;
  for (int i = row + lane; i < end; i += 64) {
    int s = csr_src[i];
    float4 hv = *(const float4*)(hp + ((unsigned)s * 16u));
    float e = hv.w + aldv;
    e = fmaxf(e, 0.2f * e);
    float ex = __expf(e);
    ss += ex;
    a0 += ex * hv.x;
    a1 += ex * hv.y;
    a2 += ex * hv.z;
  }
#pragma unroll
  for (int off = 32; off >= 1; off >>= 1) {
    a0 += __shfl_xor(a0, off, 64);
    a1 += __shfl_xor(a1, off, 64);
    a2 += __shfl_xor(a2, off, 64);
    ss += __shfl_xor(ss, off, 64);
  }
  if (lane == 0) {
    float inv = 1.f / (ss + 1e-16f);
    float o0 = a0 * inv + b3[0];
    float o1 = a1 * inv + b3[1];
    float o2 = a2 * inv + b3[2];
    float m = fmaxf(o0, fmaxf(o1, o2));
    float lse = m + logf(expf(o0 - m) + expf(o1 - m) + expf(o2 - m));
    out[n * 3 + 0] = o0 - lse;
    out[n * 3 + 1] = o1 - lse;
    out[n * 3 + 2] = o2 - lse;
  }
}

// ---------------------------------------------------------------------------

extern "C" void kernel_launch(void* const* d_in, const int* in_sizes, int n_in,
                              void* d_out, int out_size, void* d_ws, size_t ws_size,
                              hipStream_t stream) {
  const float* x   = (const float*)d_in[0];
  const int*   ei  = (const int*)d_in[1];
  const float* W1  = (const float*)d_in[2];
  const float* a1s = (const float*)d_in[3];
  const float* a1d = (const float*)d_in[4];
  const float* b1  = (const float*)d_in[5];
  const float* g1v = (const float*)d_in[6];
  const float* be1 = (const float*)d_in[7];
  const float* m1  = (const float*)d_in[8];
  const float* v1  = (const float*)d_in[9];
  const float* W2  = (const float*)d_in[10];
  const float* a2s = (const float*)d_in[11];
  const float* a2d = (const float*)d_in[12];
  const float* b2  = (const float*)d_in[13];
  const float* g2v = (const float*)d_in[14];
  const float* be2 = (const float*)d_in[15];
  const float* m2  = (const float*)d_in[16];
  const float* v2  = (const float*)d_in[17];
  const float* W3  = (const float*)d_in[18];
  const float* a3s = (const float*)d_in[19];
  const float* a3d = (const float*)d_in[20];
  const float* b3  = (const float*)d_in[21];
  float* out = (float*)d_out;

  const int N = in_sizes[0] / 128;  // 50000
  const int E = in_sizes[1] / 2;    // 850000
  const int* srcv = ei;
  const int* dstv = ei + E;

  // workspace carve-up (~75 MB)
  float* wsf  = (float*)d_ws;
  float* als1 = wsf;                  // N*4
  float* ald1 = als1 + (size_t)N * 4;
  float* als2 = ald1 + (size_t)N * 4;
  float* ald2 = als2 + (size_t)N * 4;
  float* h3p  = ald2 + (size_t)N * 4;  // N*4 (float4 rows)
  float* ald3 = h3p + (size_t)N * 4;   // N
  unsigned short* h_bf1 = (unsigned short*)(ald3 + N);  // N*256
  unsigned short* o1_bf = h_bf1 + (size_t)N * 256;      // N*256
  unsigned short* h_bf2 = o1_bf + (size_t)N * 256;      // N*128
  unsigned short* W1t   = h_bf2 + (size_t)N * 128;      // 256*128
  unsigned short* W2t   = W1t + 256 * 128;              // 128*256
  int* deg       = (int*)(W2t + 128 * 256);  // N
  int* row_start = deg + N;                  // N+1
  int* cursor    = row_start + (N + 1);      // N+1
  int* csr_src   = cursor + (N + 1);         // E
  int* bsum      = csr_src + E;              // 1024

  const int eb = (E + 255) / 256;
  const int nb = (N + 1023) / 1024;
  const int nodes4 = (N + 3) / 4;
  const int mblocks = (N + 63) / 64;

  // weight conversions
  conv_w1t_kernel<<<128, 256, 0, stream>>>(W1, W1t);
  conv_w2t_kernel<<<128, 256, 0, stream>>>(W2, W2t);

  // CSR build (shared by all 3 layers)
  hipMemsetAsync(deg, 0, (size_t)N * sizeof(int), stream);
  hist_kernel<<<eb, 256, 0, stream>>>(dstv, E, deg);
  block_sums_kernel<<<nb, 256, 0, stream>>>(deg, N, bsum);
  tiny_scan_kernel<<<1, 64, 0, stream>>>(bsum, nb);
  scan_write_kernel<<<nb, 256, 0, stream>>>(deg, N, bsum, row_start, cursor);
  scatter_kernel<<<eb, 256, 0, stream>>>(srcv, dstv, E, cursor, csr_src);

  // layer 1: h1 = x @ W1 (f32 A converted in staging), fused als1/ald1
  gemm_mfma<128, 256, true><<<mblocks, 256, 0, stream>>>(x, W1t, a1s, a1d, h_bf1, als1,
                                                         ald1, N);
  gat_aggregate<256, false><<<nodes4, 256, 0, stream>>>(
      h_bf1, als1, ald1, row_start, csr_src, b1, g1v, be1, m1, v1, o1_bf, nullptr, nullptr,
      nullptr, nullptr, nullptr, N);
  // layer 2
  gemm_mfma<256, 128, false><<<mblocks, 256, 0, stream>>>(o1_bf, W2t, a2s, a2d, h_bf2, als2,
                                                          ald2, N);
  gat_aggregate<128, true><<<nodes4, 256, 0, stream>>>(
      h_bf2, als2, ald2, row_start, csr_src, b2, g2v, be2, m2, v2, nullptr, W3, a3s, a3d,
      (float4*)h3p, ald3, N);
  // layer 3 + log_softmax
  l3_agg_kernel<<<nodes4, 256, 0, stream>>>((const float4*)h3p, ald3, row_start, csr_src,
                                            b3, out, N);
}